// Round 1
// baseline (15374.962 us; speedup 1.0000x reference)
//
#include <hip/hip_runtime.h>
#include <math.h>

#define NS 1440000

// ---- EQ chunking ----
#define EQ_L 960
#define EQ_B 1500      // EQ_B*EQ_L == NS
#define EQ_W 2560      // warm-up: worst pole r=0.99335 -> r^2560 ~ 4e-8

// ---- Compressor chunking ----
#define CP_L 2880
#define CP_B 500       // CP_B*CP_L == NS
#define CP_W 12288     // warm-up: env contraction ~e^-5..-6 over this window

// ---- Reverb chain chunking ----
#define CB  256        // chain-steps per thread block
#define RVW 40         // chain warm-up steps (0.6^40 ~ 1e-9)
#define FBC 0.6f       // feedback = 0.3 + 0.5*0.6

struct Coefs { float c[3][4][5]; };            // [stage][track][b0,b1,b2,a1,a2]
struct CompC { float atk, rel, oatk, orel, invt; };

// ===== EQ: 3-stage biquad cascade (DF2T), chunked warm-up, 2 channels/thread =====
__global__ __launch_bounds__(256) void eq_kernel(const float* __restrict__ x,
                                                 float* __restrict__ y, Coefs cf) {
  int tid = blockIdx.x * 256 + threadIdx.x;
  if (tid >= 4 * EQ_B) return;
  int chA = tid / EQ_B;            // 0..3 (tracks 0,1)
  int j   = tid % EQ_B;
  int chB = chA + 4;               // 4..7 (tracks 2,3)
  int trA = chA >> 1, trB = chB >> 1;
  float cA[3][5], cBc[3][5];
  #pragma unroll
  for (int st = 0; st < 3; ++st)
    #pragma unroll
    for (int q = 0; q < 5; ++q) { cA[st][q] = cf.c[st][trA][q]; cBc[st][q] = cf.c[st][trB][q]; }
  const float* xA = x + (size_t)chA * NS;
  const float* xB = x + (size_t)chB * NS;
  float* yA = y + (size_t)chA * NS;
  float* yB = y + (size_t)chB * NS;
  int s = j * EQ_L;
  int n0 = s - EQ_W; if (n0 < 0) n0 = 0;
  float zA[3][2] = {{0,0},{0,0},{0,0}}, zB[3][2] = {{0,0},{0,0},{0,0}};
  for (int n = n0; n < s + EQ_L; ++n) {
    float vA = xA[n], vB = xB[n];
    #pragma unroll
    for (int st = 0; st < 3; ++st) {
      float ya = fmaf(cA[st][0], vA, zA[st][0]);
      zA[st][0] = fmaf(cA[st][1], vA, zA[st][1]) - cA[st][3] * ya;
      zA[st][1] = fmaf(cA[st][2], vA, -(cA[st][4] * ya));
      vA = ya;
      float yb = fmaf(cBc[st][0], vB, zB[st][0]);
      zB[st][0] = fmaf(cBc[st][1], vB, zB[st][1]) - cBc[st][3] * yb;
      zB[st][1] = fmaf(cBc[st][2], vB, -(cBc[st][4] * yb));
      vB = yb;
    }
    if (n >= s) { yA[n] = vA; yB[n] = vB; }
  }
}

// ===== Compressor: env' = max(atk-branch, rel-branch); chunked warm-up, 2 ch/thread =====
__global__ __launch_bounds__(256) void comp_kernel(const float* __restrict__ x,
                                                   float* __restrict__ y, CompC cc) {
  int tid = blockIdx.x * 256 + threadIdx.x;
  if (tid >= 4 * CP_B) return;
  int chA = tid / CP_B, j = tid % CP_B, chB = chA + 4;
  const float* xA = x + (size_t)chA * NS;
  const float* xB = x + (size_t)chB * NS;
  float* yA = y + (size_t)chA * NS;
  float* yB = y + (size_t)chB * NS;
  int s = j * CP_L;
  int n0 = s - CP_W; if (n0 < 0) n0 = 0;
  float eA = 0.f, eB = 0.f;
  for (int n = n0; n < s + CP_L; ++n) {
    float vA = xA[n], vB = xB[n];
    float lA = fabsf(vA), lB = fabsf(vB);
    eA = fmaxf(fmaf(cc.atk, eA, cc.oatk * lA), fmaf(cc.rel, eA, cc.orel * lA));
    eB = fmaxf(fmaf(cc.atk, eB, cc.oatk * lB), fmaf(cc.rel, eB, cc.orel * lB));
    if (n >= s) {
      yA[n] = vA * powf(fmaxf(eA * cc.invt, 1.0f), -0.75f);
      yB[n] = vB * powf(fmaxf(eB * cc.invt, 1.0f), -0.75f);
    }
  }
}

// ===== Comb: y[n] = x[n] + fb*y[n-d]; phase-parallel chains, chunked with warm-up =====
__global__ __launch_bounds__(256) void comb_kernel(const float* __restrict__ xin,
                                                   float* __restrict__ acc,
                                                   int d, int J, int first) {
  int tid = blockIdx.x * 256 + threadIdx.x;
  int total = 4 * d * J;
  if (tid >= total) return;
  int rch = tid / (d * J);
  int rem = tid - rch * (d * J);
  int j = rem / d;
  int p = rem - j * d;
  const float* xi = xin + (size_t)(4 + rch) * NS;  // comp_out channels 4..7
  float* ao = acc + (size_t)rch * NS;
  int K = (NS - p + d - 1) / d;                    // chain length for this phase
  int kstart = j * CB;
  if (kstart >= K) return;
  int kend = kstart + CB; if (kend > K) kend = K;
  int k = (j == 0) ? 0 : (kstart - RVW);
  float yv = 0.f;
  int n = k * d + p;
  for (; k < kend; ++k, n += d) {
    yv = fmaf(FBC, yv, xi[n]);
    if (k >= kstart) { if (first) ao[n] = yv; else ao[n] += yv; }
  }
}

// ===== Allpass: y[n<d]=0; y[n] = -fb*u[n] + u[n-d] + fb*y[n-d] =====
__global__ __launch_bounds__(256) void allpass_kernel(const float* __restrict__ xin,
                                                      float* __restrict__ yout,
                                                      int d, int J, float inscale) {
  int tid = blockIdx.x * 256 + threadIdx.x;
  int total = 4 * d * J;
  if (tid >= total) return;
  int rch = tid / (d * J);
  int rem = tid - rch * (d * J);
  int j = rem / d;
  int p = rem - j * d;
  const float* xi = xin + (size_t)rch * NS;
  float* yo = yout + (size_t)rch * NS;
  int K = (NS - p + d - 1) / d;
  int kstart = j * CB;
  if (kstart >= K) return;
  int kend = kstart + CB; if (kend > K) kend = K;
  float yv = 0.f;
  int k;
  if (j == 0) { yo[p] = 0.f; k = 1; }              // k=0 output is exactly 0
  else        { k = kstart - RVW; }                // >= CB-RVW >= 1
  int n = k * d + p;
  for (; k < kend; ++k, n += d) {
    float u  = inscale * xi[n];
    float up = inscale * xi[n - d];
    yv = fmaf(FBC, yv, fmaf(-FBC, u, up));
    if (k >= kstart) yo[n] = yv;
  }
}

// ===== Pan/volume gains (tiny, avoids per-sample sincos) =====
__global__ void gains_kernel(const float* __restrict__ vol, const float* __restrict__ pan,
                             float* __restrict__ g) {
  int t = threadIdx.x;
  if (t < 4) {
    float angle = (pan[t] + 1.0f) * 0.25f * 3.14159265358979323846f;
    g[2 * t]     = vol[t] * cosf(angle);
    g[2 * t + 1] = vol[t] * sinf(angle);
  }
}

// ===== Final mix: dry/wet blend for tracks 2,3; einsum over tracks; clip =====
__global__ __launch_bounds__(256) void mix_kernel(const float* __restrict__ cp,
                                                  const float* __restrict__ wet,
                                                  const float* __restrict__ g,
                                                  float* __restrict__ out) {
  int i = blockIdx.x * 256 + threadIdx.x;
  if (i >= NS / 4) return;
  size_t n = (size_t)i * 4;
  float g0 = g[0], g1 = g[1], g2 = g[2], g3 = g[3];
  float g4 = g[4], g5 = g[5], g6 = g[6], g7 = g[7];
  const float CEIL = 0.89125093813374556f;  // 10^(-1/20)
  float4 t0l = *(const float4*)(cp + 0 * (size_t)NS + n);
  float4 t0r = *(const float4*)(cp + 1 * (size_t)NS + n);
  float4 t1l = *(const float4*)(cp + 2 * (size_t)NS + n);
  float4 t1r = *(const float4*)(cp + 3 * (size_t)NS + n);
  float4 t2l = *(const float4*)(cp + 4 * (size_t)NS + n);
  float4 t2r = *(const float4*)(cp + 5 * (size_t)NS + n);
  float4 t3l = *(const float4*)(cp + 6 * (size_t)NS + n);
  float4 t3r = *(const float4*)(cp + 7 * (size_t)NS + n);
  float4 w2l = *(const float4*)(wet + 0 * (size_t)NS + n);
  float4 w2r = *(const float4*)(wet + 1 * (size_t)NS + n);
  float4 w3l = *(const float4*)(wet + 2 * (size_t)NS + n);
  float4 w3r = *(const float4*)(wet + 3 * (size_t)NS + n);
  float4 outl, outr;
  float* pl = &outl.x; float* pr = &outr.x;
  const float* a0 = &t0l.x; const float* a1 = &t0r.x;
  const float* a2 = &t1l.x; const float* a3 = &t1r.x;
  const float* a4 = &t2l.x; const float* a5 = &t2r.x;
  const float* a6 = &t3l.x; const float* a7 = &t3r.x;
  const float* b4 = &w2l.x; const float* b5 = &w2r.x;
  const float* b6 = &w3l.x; const float* b7 = &w3r.x;
  #pragma unroll
  for (int c = 0; c < 4; ++c) {
    float x4 = 0.7f * a4[c] + 0.3f * b4[c];
    float x5 = 0.7f * a5[c] + 0.3f * b5[c];
    float x6 = 0.7f * a6[c] + 0.3f * b6[c];
    float x7 = 0.7f * a7[c] + 0.3f * b7[c];
    float L = g0 * a0[c] + g2 * a2[c] + g4 * x4 + g6 * x6;
    float R = g1 * a1[c] + g3 * a3[c] + g5 * x5 + g7 * x7;
    pl[c] = fminf(fmaxf(L, -CEIL), CEIL);
    pr[c] = fminf(fmaxf(R, -CEIL), CEIL);
  }
  *(float4*)(out + n) = outl;
  *(float4*)(out + (size_t)NS + n) = outr;
}

// ---------------- Host side ----------------
static void peak_coefs(double f, double gdb, double q, float* o) {
  double A  = pow(10.0, gdb / 40.0);
  double w0 = 2.0 * M_PI * f / 48000.0;
  double al = sin(w0) / (2.0 * q);
  double a0 = 1.0 + al / A;
  o[0] = (float)((1.0 + al * A) / a0);
  o[1] = (float)(-2.0 * cos(w0) / a0);
  o[2] = (float)((1.0 - al * A) / a0);
  o[3] = (float)(-2.0 * cos(w0) / a0);
  o[4] = (float)((1.0 - al / A) / a0);
}

extern "C" void kernel_launch(void* const* d_in, const int* in_sizes, int n_in,
                              void* d_out, int out_size, void* d_ws, size_t ws_size,
                              hipStream_t stream) {
  const float* tracks = (const float*)d_in[0];
  const float* vols   = (const float*)d_in[1];
  const float* pans   = (const float*)d_in[2];
  float* out = (float*)d_out;
  float* w = (float*)d_ws;
  // ws layout (floats): [0,8N) EQ out -> reused: [0,4N) comb acc then ap81 out,
  //                     [4N,8N) ap240 out; [8N,16N) comp out; [16N,16N+8) gains
  float* eqbuf = w;
  float* cpbuf = w + (size_t)8 * NS;
  float* combb = w;
  float* apb   = w + (size_t)4 * NS;
  float* wet2  = w;
  float* gbuf  = w + (size_t)16 * NS;

  // EQ coefficients (mirror reference's float64 math then cast to f32)
  Coefs cf;
  const float ident[5] = {1.f, 0.f, 0.f, 0.f, 0.f};
  // presets[track][band] = {freq, gain_db, q}; nbands per track: 3,2,2,1
  const double P[4][3][3] = {
    {{300, -3, 0.7}, {3000, 3, 1.0}, {8000, 2, 0.7}},   // voice
    {{80, 2, 0.7},   {5000, 1, 1.0}, {0, 0, 0}},        // music
    {{200, -2, 0.7}, {6000, -1, 0.7}, {0, 0, 0}},       // ambient
    {{1000, 2, 1.0}, {0, 0, 0},      {0, 0, 0}},        // fx
  };
  const int nb[4] = {3, 2, 2, 1};
  for (int t = 0; t < 4; ++t)
    for (int s = 0; s < 3; ++s) {
      if (s < nb[t]) peak_coefs(P[t][s][0], P[t][s][1], P[t][s][2], cf.c[s][t]);
      else for (int q = 0; q < 5; ++q) cf.c[s][t][q] = ident[q];
    }

  CompC cc;
  double atk = exp(-1.0 / 480.0), rel = exp(-1.0 / 4800.0);
  cc.atk  = (float)atk;  cc.rel  = (float)rel;
  cc.oatk = (float)(1.0 - atk); cc.orel = (float)(1.0 - rel);
  cc.invt = (float)(1.0 / (pow(10.0, -18.0 / 20.0) + 1e-8));

  hipLaunchKernelGGL(eq_kernel, dim3((4 * EQ_B + 255) / 256), dim3(256), 0, stream,
                     tracks, eqbuf, cf);
  hipLaunchKernelGGL(comp_kernel, dim3((4 * CP_B + 255) / 256), dim3(256), 0, stream,
                     eqbuf, cpbuf, cc);

  const int combd[4] = {1440, 1627, 1828, 2030};  // int(1440*{1,1.13,1.27,1.41})
  for (int i = 0; i < 4; ++i) {
    int d = combd[i];
    int K = (NS + d - 1) / d;
    int J = (K + CB - 1) / CB;
    int total = 4 * d * J;
    hipLaunchKernelGGL(comb_kernel, dim3((total + 255) / 256), dim3(256), 0, stream,
                       cpbuf, combb, d, J, (i == 0) ? 1 : 0);
  }
  {
    int d = 240, K = (NS + d - 1) / d, J = (K + CB - 1) / CB, total = 4 * d * J;
    hipLaunchKernelGGL(allpass_kernel, dim3((total + 255) / 256), dim3(256), 0, stream,
                       combb, apb, d, J, 0.25f);  // fold the /4 comb average into input
  }
  {
    int d = 81, K = (NS + d - 1) / d, J = (K + CB - 1) / CB, total = 4 * d * J;
    hipLaunchKernelGGL(allpass_kernel, dim3((total + 255) / 256), dim3(256), 0, stream,
                       apb, wet2, d, J, 1.0f);
  }
  hipLaunchKernelGGL(gains_kernel, dim3(1), dim3(64), 0, stream, vols, pans, gbuf);
  hipLaunchKernelGGL(mix_kernel, dim3((NS / 4 + 255) / 256), dim3(256), 0, stream,
                     cpbuf, wet2, gbuf, out);
}

// Round 2
// 5673.306 us; speedup vs baseline: 2.7101x; 2.7101x over previous
//
#include <hip/hip_runtime.h>
#include <math.h>

#define NS 1440000
#define L  720          // chunk length (samples) for chunk-major layout
#define NC 2000         // chunks per channel; L*NC == NS

// EQ warm-up: worst pole r=0.99335 -> r^2560 ~ 4e-8. 2560 = 4*720 - 320.
#define EQ_JBACK 4
#define EQ_I0    320
// Compressor warm-up 12288 (proven absmax 1.95e-3). 12288 = 18*720 - 672.
#define CP_JBACK 18
#define CP_I0    672

// ---- Reverb chain chunking ----
#define CB  256        // chain-steps per thread
#define RVW 40         // chain warm-up steps (0.6^40 ~ 1e-9)
#define FBC 0.6f       // feedback = 0.3 + 0.5*0.6

struct Coefs { float c[3][4][5]; };            // [stage][track][b0,b1,b2,a1,a2]
struct CompC { float atk, rel, oatk, orel, invt; };

// ===== Transpose: x[ch][n] -> XT[ch][i][j], n = j*L + i. Writes coalesced. =====
__global__ __launch_bounds__(256) void transpose_in(const float* __restrict__ x,
                                                    float* __restrict__ XT) {
  int idx = blockIdx.x * 256 + threadIdx.x;       // over 8*NS
  int j = idx % NC;
  int rest = idx / NC;
  int i = rest % L;
  int ch = rest / L;
  XT[idx] = x[(size_t)ch * NS + (size_t)j * L + i];
}

// ===== EQ: 3-stage biquad cascade, chunk-major coalesced, chunked warm-up =====
__global__ __launch_bounds__(64) void eq_kernel(const float* __restrict__ XT,
                                                float* __restrict__ ET, Coefs cf) {
  int tid = blockIdx.x * 64 + threadIdx.x;        // over 8*NC
  int ch = tid / NC, j = tid % NC;
  int tr = ch >> 1;
  float c[3][5];
  #pragma unroll
  for (int st = 0; st < 3; ++st)
    #pragma unroll
    for (int q = 0; q < 5; ++q) c[st][q] = cf.c[st][tr][q];
  const float* X = XT + (size_t)ch * NS;
  float* E = ET + (size_t)ch * NS;
  float z[3][2] = {{0,0},{0,0},{0,0}};
  int jj0, i0;
  if (j >= EQ_JBACK) { jj0 = j - EQ_JBACK; i0 = EQ_I0; } else { jj0 = 0; i0 = 0; }
  // warm-up chunks (no writes)
  for (int jj = jj0; jj < j; ++jj) {
    int ib = (jj == jj0) ? i0 : 0;
    const float* p = X + (size_t)ib * NC + jj;
    for (int i = ib; i < L; ++i, p += NC) {
      float v = *p;
      #pragma unroll
      for (int st = 0; st < 3; ++st) {
        float ya = fmaf(c[st][0], v, z[st][0]);
        z[st][0] = fmaf(c[st][1], v, z[st][1]) - c[st][3] * ya;
        z[st][1] = fmaf(c[st][2], v, -(c[st][4] * ya));
        v = ya;
      }
    }
  }
  // output chunk
  const float* p = X + j;
  float* q = E + j;
  for (int i = 0; i < L; ++i, p += NC, q += NC) {
    float v = *p;
    #pragma unroll
    for (int st = 0; st < 3; ++st) {
      float ya = fmaf(c[st][0], v, z[st][0]);
      z[st][0] = fmaf(c[st][1], v, z[st][1]) - c[st][3] * ya;
      z[st][1] = fmaf(c[st][2], v, -(c[st][4] * ya));
      v = ya;
    }
    *q = v;
  }
}

// ===== Compressor: chunk-major coalesced reads, natural-layout writes =====
__global__ __launch_bounds__(64) void comp_kernel(const float* __restrict__ ET,
                                                  float* __restrict__ Y, CompC cc) {
  int tid = blockIdx.x * 64 + threadIdx.x;        // over 8*NC
  int ch = tid / NC, j = tid % NC;
  const float* E = ET + (size_t)ch * NS;
  float env = 0.f;
  int jj0, i0;
  if (j >= CP_JBACK) { jj0 = j - CP_JBACK; i0 = CP_I0; } else { jj0 = 0; i0 = 0; }
  for (int jj = jj0; jj < j; ++jj) {
    int ib = (jj == jj0) ? i0 : 0;
    const float* p = E + (size_t)ib * NC + jj;
    for (int i = ib; i < L; ++i, p += NC) {
      float lvl = fabsf(*p);
      env = fmaxf(fmaf(cc.atk, env, cc.oatk * lvl), fmaf(cc.rel, env, cc.orel * lvl));
    }
  }
  const float* p = E + j;
  float* py = Y + (size_t)ch * NS + (size_t)j * L;
  for (int i = 0; i < L; ++i, p += NC) {
    float v = *p;
    float lvl = fabsf(v);
    env = fmaxf(fmaf(cc.atk, env, cc.oatk * lvl), fmaf(cc.rel, env, cc.orel * lvl));
    py[i] = v * powf(fmaxf(env * cc.invt, 1.0f), -0.75f);
  }
}

// ===== Comb: y[n] = x[n] + fb*y[n-d]; phase-parallel chains, chunked with warm-up =====
__global__ __launch_bounds__(256) void comb_kernel(const float* __restrict__ xin,
                                                   float* __restrict__ acc,
                                                   int d, int J, int first) {
  int tid = blockIdx.x * 256 + threadIdx.x;
  int total = 4 * d * J;
  if (tid >= total) return;
  int rch = tid / (d * J);
  int rem = tid - rch * (d * J);
  int j = rem / d;
  int p = rem - j * d;
  const float* xi = xin + (size_t)(4 + rch) * NS;  // comp_out channels 4..7
  float* ao = acc + (size_t)rch * NS;
  int K = (NS - p + d - 1) / d;                    // chain length for this phase
  int kstart = j * CB;
  if (kstart >= K) return;
  int kend = kstart + CB; if (kend > K) kend = K;
  int k = (j == 0) ? 0 : (kstart - RVW);
  float yv = 0.f;
  int n = k * d + p;
  for (; k < kend; ++k, n += d) {
    yv = fmaf(FBC, yv, xi[n]);
    if (k >= kstart) { if (first) ao[n] = yv; else ao[n] += yv; }
  }
}

// ===== Allpass: y[n<d]=0; y[n] = -fb*u[n] + u[n-d] + fb*y[n-d] =====
__global__ __launch_bounds__(256) void allpass_kernel(const float* __restrict__ xin,
                                                      float* __restrict__ yout,
                                                      int d, int J, float inscale) {
  int tid = blockIdx.x * 256 + threadIdx.x;
  int total = 4 * d * J;
  if (tid >= total) return;
  int rch = tid / (d * J);
  int rem = tid - rch * (d * J);
  int j = rem / d;
  int p = rem - j * d;
  const float* xi = xin + (size_t)rch * NS;
  float* yo = yout + (size_t)rch * NS;
  int K = (NS - p + d - 1) / d;
  int kstart = j * CB;
  if (kstart >= K) return;
  int kend = kstart + CB; if (kend > K) kend = K;
  float yv = 0.f;
  int k;
  if (j == 0) { yo[p] = 0.f; k = 1; }              // k=0 output is exactly 0
  else        { k = kstart - RVW; }                // >= CB-RVW >= 1
  int n = k * d + p;
  for (; k < kend; ++k, n += d) {
    float u  = inscale * xi[n];
    float up = inscale * xi[n - d];
    yv = fmaf(FBC, yv, fmaf(-FBC, u, up));
    if (k >= kstart) yo[n] = yv;
  }
}

// ===== Pan/volume gains =====
__global__ void gains_kernel(const float* __restrict__ vol, const float* __restrict__ pan,
                             float* __restrict__ g) {
  int t = threadIdx.x;
  if (t < 4) {
    float angle = (pan[t] + 1.0f) * 0.25f * 3.14159265358979323846f;
    g[2 * t]     = vol[t] * cosf(angle);
    g[2 * t + 1] = vol[t] * sinf(angle);
  }
}

// ===== Final mix: dry/wet blend for tracks 2,3; einsum over tracks; clip =====
__global__ __launch_bounds__(256) void mix_kernel(const float* __restrict__ cp,
                                                  const float* __restrict__ wet,
                                                  const float* __restrict__ g,
                                                  float* __restrict__ out) {
  int i = blockIdx.x * 256 + threadIdx.x;
  if (i >= NS / 4) return;
  size_t n = (size_t)i * 4;
  float g0 = g[0], g1 = g[1], g2 = g[2], g3 = g[3];
  float g4 = g[4], g5 = g[5], g6 = g[6], g7 = g[7];
  const float CEIL = 0.89125093813374556f;  // 10^(-1/20)
  float4 t0l = *(const float4*)(cp + 0 * (size_t)NS + n);
  float4 t0r = *(const float4*)(cp + 1 * (size_t)NS + n);
  float4 t1l = *(const float4*)(cp + 2 * (size_t)NS + n);
  float4 t1r = *(const float4*)(cp + 3 * (size_t)NS + n);
  float4 t2l = *(const float4*)(cp + 4 * (size_t)NS + n);
  float4 t2r = *(const float4*)(cp + 5 * (size_t)NS + n);
  float4 t3l = *(const float4*)(cp + 6 * (size_t)NS + n);
  float4 t3r = *(const float4*)(cp + 7 * (size_t)NS + n);
  float4 w2l = *(const float4*)(wet + 0 * (size_t)NS + n);
  float4 w2r = *(const float4*)(wet + 1 * (size_t)NS + n);
  float4 w3l = *(const float4*)(wet + 2 * (size_t)NS + n);
  float4 w3r = *(const float4*)(wet + 3 * (size_t)NS + n);
  float4 outl, outr;
  float* pl = &outl.x; float* pr = &outr.x;
  const float* a0 = &t0l.x; const float* a1 = &t0r.x;
  const float* a2 = &t1l.x; const float* a3 = &t1r.x;
  const float* a4 = &t2l.x; const float* a5 = &t2r.x;
  const float* a6 = &t3l.x; const float* a7 = &t3r.x;
  const float* b4 = &w2l.x; const float* b5 = &w2r.x;
  const float* b6 = &w3l.x; const float* b7 = &w3r.x;
  #pragma unroll
  for (int c = 0; c < 4; ++c) {
    float x4 = 0.7f * a4[c] + 0.3f * b4[c];
    float x5 = 0.7f * a5[c] + 0.3f * b5[c];
    float x6 = 0.7f * a6[c] + 0.3f * b6[c];
    float x7 = 0.7f * a7[c] + 0.3f * b7[c];
    float Lv = g0 * a0[c] + g2 * a2[c] + g4 * x4 + g6 * x6;
    float Rv = g1 * a1[c] + g3 * a3[c] + g5 * x5 + g7 * x7;
    pl[c] = fminf(fmaxf(Lv, -CEIL), CEIL);
    pr[c] = fminf(fmaxf(Rv, -CEIL), CEIL);
  }
  *(float4*)(out + n) = outl;
  *(float4*)(out + (size_t)NS + n) = outr;
}

// ---------------- Host side ----------------
static void peak_coefs(double f, double gdb, double q, float* o) {
  double A  = pow(10.0, gdb / 40.0);
  double w0 = 2.0 * M_PI * f / 48000.0;
  double al = sin(w0) / (2.0 * q);
  double a0 = 1.0 + al / A;
  o[0] = (float)((1.0 + al * A) / a0);
  o[1] = (float)(-2.0 * cos(w0) / a0);
  o[2] = (float)((1.0 - al * A) / a0);
  o[3] = (float)(-2.0 * cos(w0) / a0);
  o[4] = (float)((1.0 - al / A) / a0);
}

extern "C" void kernel_launch(void* const* d_in, const int* in_sizes, int n_in,
                              void* d_out, int out_size, void* d_ws, size_t ws_size,
                              hipStream_t stream) {
  const float* tracks = (const float*)d_in[0];
  const float* vols   = (const float*)d_in[1];
  const float* pans   = (const float*)d_in[2];
  float* out = (float*)d_out;
  float* w = (float*)d_ws;
  // ws layout (floats):
  //  [0,8N)   : XT (transposed input) -> overwritten by comp output Y (natural)
  //  [8N,16N) : ET (EQ output, chunk-major) -> after comp: comb acc [8N,12N),
  //             ap240 out [12N,16N), ap81 out back to [8N,12N) = wet
  //  gains at [12N, 12N+8) after ap81 (ap240 buffer dead)
  float* XT   = w;
  float* ET   = w + (size_t)8 * NS;
  float* cpbuf = w;                       // comp output, natural layout
  float* combb = w + (size_t)8 * NS;      // comb accumulator (ET dead)
  float* apb   = w + (size_t)12 * NS;     // allpass d=240 output
  float* wet2  = w + (size_t)8 * NS;      // allpass d=81 output (comb acc dead)
  float* gbuf  = w + (size_t)12 * NS;     // gains (apb dead after ap81)

  Coefs cf;
  const float ident[5] = {1.f, 0.f, 0.f, 0.f, 0.f};
  const double P[4][3][3] = {
    {{300, -3, 0.7}, {3000, 3, 1.0}, {8000, 2, 0.7}},   // voice
    {{80, 2, 0.7},   {5000, 1, 1.0}, {0, 0, 0}},        // music
    {{200, -2, 0.7}, {6000, -1, 0.7}, {0, 0, 0}},       // ambient
    {{1000, 2, 1.0}, {0, 0, 0},      {0, 0, 0}},        // fx
  };
  const int nb[4] = {3, 2, 2, 1};
  for (int t = 0; t < 4; ++t)
    for (int s = 0; s < 3; ++s) {
      if (s < nb[t]) peak_coefs(P[t][s][0], P[t][s][1], P[t][s][2], cf.c[s][t]);
      else for (int q = 0; q < 5; ++q) cf.c[s][t][q] = ident[q];
    }

  CompC cc;
  double atk = exp(-1.0 / 480.0), rel = exp(-1.0 / 4800.0);
  cc.atk  = (float)atk;  cc.rel  = (float)rel;
  cc.oatk = (float)(1.0 - atk); cc.orel = (float)(1.0 - rel);
  cc.invt = (float)(1.0 / (pow(10.0, -18.0 / 20.0) + 1e-8));

  hipLaunchKernelGGL(transpose_in, dim3(8 * NS / 256), dim3(256), 0, stream,
                     tracks, XT);
  // 8*NC = 16000 threads, blocks of 64 -> 250 blocks spread across CUs
  hipLaunchKernelGGL(eq_kernel, dim3(8 * NC / 64), dim3(64), 0, stream,
                     XT, ET, cf);
  hipLaunchKernelGGL(comp_kernel, dim3(8 * NC / 64), dim3(64), 0, stream,
                     ET, cpbuf, cc);

  const int combd[4] = {1440, 1627, 1828, 2030};  // int(1440*{1,1.13,1.27,1.41})
  for (int i = 0; i < 4; ++i) {
    int d = combd[i];
    int K = (NS + d - 1) / d;
    int J = (K + CB - 1) / CB;
    int total = 4 * d * J;
    hipLaunchKernelGGL(comb_kernel, dim3((total + 255) / 256), dim3(256), 0, stream,
                       cpbuf, combb, d, J, (i == 0) ? 1 : 0);
  }
  {
    int d = 240, K = (NS + d - 1) / d, J = (K + CB - 1) / CB, total = 4 * d * J;
    hipLaunchKernelGGL(allpass_kernel, dim3((total + 255) / 256), dim3(256), 0, stream,
                       combb, apb, d, J, 0.25f);  // fold the /4 comb average into input
  }
  {
    int d = 81, K = (NS + d - 1) / d, J = (K + CB - 1) / CB, total = 4 * d * J;
    hipLaunchKernelGGL(allpass_kernel, dim3((total + 255) / 256), dim3(256), 0, stream,
                       apb, wet2, d, J, 1.0f);
  }
  hipLaunchKernelGGL(gains_kernel, dim3(1), dim3(64), 0, stream, vols, pans, gbuf);
  hipLaunchKernelGGL(mix_kernel, dim3((NS / 4 + 255) / 256), dim3(256), 0, stream,
                     cpbuf, wet2, gbuf, out);
}

// Round 3
// 777.302 us; speedup vs baseline: 19.7799x; 7.2987x over previous
//
#include <hip/hip_runtime.h>
#include <math.h>

#define NS 1440000
#define L  720          // chunk length (samples) for chunk-major layout
#define NC 2000         // chunks per channel; L*NC == NS
#define TI 45           // i-tiles for transpose (720/16)
#define TJ 125          // j-tiles for transpose (2000/16)

// EQ warm-up: worst pole r=0.99335 -> r^2560 ~ 4e-8. 2560 = 4*720 - 320.
#define EQ_JBACK 4
#define EQ_I0    320
#define EQ_U     20     // strip size: divides 400/2U=10 and 720/2U=18 exactly
// Compressor warm-up 12288 (proven absmax 1.95e-3). 12288 = 18*720 - 672.
#define CP_JBACK 18
#define CP_I0    672
#define CP_U     24     // strip size: 48/(2U)=1, 720/(2U)=15 exactly

// ---- Reverb chain chunking ----
#define CB  128        // chain-steps per thread
#define RVW 40         // chain warm-up steps (0.6^40 ~ 1e-9)
#define FBC 0.6f       // feedback = 0.3 + 0.5*0.6

struct Coefs { float c[3][4][5]; };            // [stage][track][b0,b1,b2,a1,a2]
struct CompC { float atk, rel, oatk, orel, invt; };

// ===== Tiled transpose: x[ch][j*L+i] -> XT[ch][i*NC+j], both sides coalesced =====
__global__ __launch_bounds__(256) void transpose_in(const float* __restrict__ x,
                                                    float* __restrict__ XT) {
  __shared__ float t[16][17];
  int b = blockIdx.x;
  int ch = b / (TI * TJ);
  int r  = b % (TI * TJ);
  int it = r / TJ, jt = r % TJ;
  int tx = threadIdx.x & 15, ty = threadIdx.x >> 4;
  int i0 = it * 16, j0 = jt * 16;
  t[ty][tx] = x[(size_t)ch * NS + (size_t)(j0 + ty) * L + (i0 + tx)];
  __syncthreads();
  XT[(size_t)ch * NS + (size_t)(i0 + ty) * NC + (j0 + tx)] = t[tx][ty];
}

// ===== EQ: 3-stage biquad cascade, chunk-major, double-buffered register prefetch =====
#define EQ_STEP(VV)                                                        \
  {                                                                        \
    float v = (VV);                                                        \
    _Pragma("unroll")                                                      \
    for (int st = 0; st < 3; ++st) {                                       \
      float ya = fmaf(c[st][0], v, z[st][0]);                              \
      z[st][0] = fmaf(c[st][1], v, z[st][1]) - c[st][3] * ya;              \
      z[st][1] = fmaf(c[st][2], v, -(c[st][4] * ya));                      \
      v = ya;                                                              \
    }                                                                      \
    vout = v;                                                              \
  }

__global__ __launch_bounds__(64) void eq_kernel(const float* __restrict__ XT,
                                                float* __restrict__ ET, Coefs cf) {
  int tid = blockIdx.x * 64 + threadIdx.x;        // over 8*NC
  int ch = tid / NC, j = tid % NC;
  int tr = ch >> 1;
  float c[3][5];
  #pragma unroll
  for (int st = 0; st < 3; ++st)
    #pragma unroll
    for (int q = 0; q < 5; ++q) c[st][q] = cf.c[st][tr][q];
  const float* X = XT + (size_t)ch * NS;
  float* E = ET + (size_t)ch * NS;
  float z[3][2] = {{0,0},{0,0},{0,0}};
  float vout;
  int jj0 = (j >= EQ_JBACK) ? (j - EQ_JBACK) : 0;
  int i0  = (j >= EQ_JBACK) ? EQ_I0 : 0;
  float b0[EQ_U], b1[EQ_U];
  // ---- warm-up passes (no writes) ----
  for (int jj = jj0; jj < j; ++jj) {
    int ib = (jj == jj0) ? i0 : 0;
    const float* p = X + (size_t)ib * NC + jj;
    int np = (L - ib) / (2 * EQ_U);
    #pragma unroll
    for (int u = 0; u < EQ_U; ++u) b0[u] = p[(size_t)u * NC];
    p += (size_t)EQ_U * NC;
    for (int k = 0; k < np - 1; ++k) {
      #pragma unroll
      for (int u = 0; u < EQ_U; ++u) b1[u] = p[(size_t)u * NC];
      p += (size_t)EQ_U * NC;
      #pragma unroll
      for (int u = 0; u < EQ_U; ++u) EQ_STEP(b0[u]);
      #pragma unroll
      for (int u = 0; u < EQ_U; ++u) b0[u] = p[(size_t)u * NC];
      p += (size_t)EQ_U * NC;
      #pragma unroll
      for (int u = 0; u < EQ_U; ++u) EQ_STEP(b1[u]);
    }
    #pragma unroll
    for (int u = 0; u < EQ_U; ++u) b1[u] = p[(size_t)u * NC];
    #pragma unroll
    for (int u = 0; u < EQ_U; ++u) EQ_STEP(b0[u]);
    #pragma unroll
    for (int u = 0; u < EQ_U; ++u) EQ_STEP(b1[u]);
  }
  // ---- output chunk (with coalesced stores) ----
  {
    const float* p = X + j;
    float* q = E + j;
    int np = L / (2 * EQ_U);                       // 18
    #pragma unroll
    for (int u = 0; u < EQ_U; ++u) b0[u] = p[(size_t)u * NC];
    p += (size_t)EQ_U * NC;
    for (int k = 0; k < np - 1; ++k) {
      #pragma unroll
      for (int u = 0; u < EQ_U; ++u) b1[u] = p[(size_t)u * NC];
      p += (size_t)EQ_U * NC;
      #pragma unroll
      for (int u = 0; u < EQ_U; ++u) { EQ_STEP(b0[u]); q[(size_t)u * NC] = vout; }
      q += (size_t)EQ_U * NC;
      #pragma unroll
      for (int u = 0; u < EQ_U; ++u) b0[u] = p[(size_t)u * NC];
      p += (size_t)EQ_U * NC;
      #pragma unroll
      for (int u = 0; u < EQ_U; ++u) { EQ_STEP(b1[u]); q[(size_t)u * NC] = vout; }
      q += (size_t)EQ_U * NC;
    }
    #pragma unroll
    for (int u = 0; u < EQ_U; ++u) b1[u] = p[(size_t)u * NC];
    #pragma unroll
    for (int u = 0; u < EQ_U; ++u) { EQ_STEP(b0[u]); q[(size_t)u * NC] = vout; }
    q += (size_t)EQ_U * NC;
    #pragma unroll
    for (int u = 0; u < EQ_U; ++u) { EQ_STEP(b1[u]); q[(size_t)u * NC] = vout; }
  }
}

// ===== Compressor: double-buffered register prefetch =====
#define CP_STEP(VV)                                                            \
  {                                                                            \
    float lvl = fabsf(VV);                                                     \
    env = fmaxf(fmaf(cc.atk, env, cc.oatk * lvl), fmaf(cc.rel, env, cc.orel * lvl)); \
  }

__global__ __launch_bounds__(64) void comp_kernel(const float* __restrict__ ET,
                                                  float* __restrict__ Y, CompC cc) {
  int tid = blockIdx.x * 64 + threadIdx.x;        // over 8*NC
  int ch = tid / NC, j = tid % NC;
  const float* E = ET + (size_t)ch * NS;
  float env = 0.f;
  int jj0 = (j >= CP_JBACK) ? (j - CP_JBACK) : 0;
  int i0  = (j >= CP_JBACK) ? CP_I0 : 0;
  float b0[CP_U], b1[CP_U];
  // ---- warm-up passes ----
  for (int jj = jj0; jj < j; ++jj) {
    int ib = (jj == jj0) ? i0 : 0;
    const float* p = E + (size_t)ib * NC + jj;
    int np = (L - ib) / (2 * CP_U);                // 48->1, 720->15
    #pragma unroll
    for (int u = 0; u < CP_U; ++u) b0[u] = p[(size_t)u * NC];
    p += (size_t)CP_U * NC;
    for (int k = 0; k < np - 1; ++k) {
      #pragma unroll
      for (int u = 0; u < CP_U; ++u) b1[u] = p[(size_t)u * NC];
      p += (size_t)CP_U * NC;
      #pragma unroll
      for (int u = 0; u < CP_U; ++u) CP_STEP(b0[u]);
      #pragma unroll
      for (int u = 0; u < CP_U; ++u) b0[u] = p[(size_t)u * NC];
      p += (size_t)CP_U * NC;
      #pragma unroll
      for (int u = 0; u < CP_U; ++u) CP_STEP(b1[u]);
    }
    #pragma unroll
    for (int u = 0; u < CP_U; ++u) b1[u] = p[(size_t)u * NC];
    #pragma unroll
    for (int u = 0; u < CP_U; ++u) CP_STEP(b0[u]);
    #pragma unroll
    for (int u = 0; u < CP_U; ++u) CP_STEP(b1[u]);
  }
  // ---- output chunk: gr = m^-0.75 = sqrt(sqrt(m)) * rcp(m), m >= 1 ----
  {
    const float* p = E + j;
    float* py = Y + (size_t)ch * NS + (size_t)j * L;   // natural layout
    int np = L / (2 * CP_U);                            // 15
    #pragma unroll
    for (int u = 0; u < CP_U; ++u) b0[u] = p[(size_t)u * NC];
    p += (size_t)CP_U * NC;
    for (int k = 0; k < np - 1; ++k) {
      #pragma unroll
      for (int u = 0; u < CP_U; ++u) b1[u] = p[(size_t)u * NC];
      p += (size_t)CP_U * NC;
      #pragma unroll
      for (int u = 0; u < CP_U; ++u) {
        float v = b0[u]; CP_STEP(v);
        float m = fmaxf(env * cc.invt, 1.0f);
        py[u] = v * (sqrtf(sqrtf(m)) * __builtin_amdgcn_rcpf(m));
      }
      py += CP_U;
      #pragma unroll
      for (int u = 0; u < CP_U; ++u) b0[u] = p[(size_t)u * NC];
      p += (size_t)CP_U * NC;
      #pragma unroll
      for (int u = 0; u < CP_U; ++u) {
        float v = b1[u]; CP_STEP(v);
        float m = fmaxf(env * cc.invt, 1.0f);
        py[u] = v * (sqrtf(sqrtf(m)) * __builtin_amdgcn_rcpf(m));
      }
      py += CP_U;
    }
    #pragma unroll
    for (int u = 0; u < CP_U; ++u) b1[u] = p[(size_t)u * NC];
    #pragma unroll
    for (int u = 0; u < CP_U; ++u) {
      float v = b0[u]; CP_STEP(v);
      float m = fmaxf(env * cc.invt, 1.0f);
      py[u] = v * (sqrtf(sqrtf(m)) * __builtin_amdgcn_rcpf(m));
    }
    py += CP_U;
    #pragma unroll
    for (int u = 0; u < CP_U; ++u) {
      float v = b1[u]; CP_STEP(v);
      float m = fmaxf(env * cc.invt, 1.0f);
      py[u] = v * (sqrtf(sqrtf(m)) * __builtin_amdgcn_rcpf(m));
    }
  }
}

// ===== Comb: y[n] = x[n] + fb*y[n-d]; phase-parallel chains =====
__global__ __launch_bounds__(256) void comb_kernel(const float* __restrict__ xin,
                                                   float* __restrict__ acc,
                                                   int d, int J, int first) {
  int tid = blockIdx.x * 256 + threadIdx.x;
  int total = 4 * d * J;
  if (tid >= total) return;
  int rch = tid / (d * J);
  int rem = tid - rch * (d * J);
  int j = rem / d;
  int p = rem - j * d;
  const float* xi = xin + (size_t)(4 + rch) * NS;  // comp_out channels 4..7
  float* ao = acc + (size_t)rch * NS;
  int K = (NS - p + d - 1) / d;                    // chain length for this phase
  int kstart = j * CB;
  if (kstart >= K) return;
  int kend = kstart + CB; if (kend > K) kend = K;
  float yv = 0.f;
  int k = (j == 0) ? 0 : (kstart - RVW);
  int n = k * d + p;
  if (j != 0) {
    #pragma unroll 8
    for (; k < kstart; ++k, n += d) yv = fmaf(FBC, yv, xi[n]);
  }
  if (first) {
    #pragma unroll 8
    for (; k < kend; ++k, n += d) { yv = fmaf(FBC, yv, xi[n]); ao[n] = yv; }
  } else {
    #pragma unroll 8
    for (; k < kend; ++k, n += d) { yv = fmaf(FBC, yv, xi[n]); ao[n] += yv; }
  }
}

// ===== Allpass: y[n<d]=0; y[n] = -fb*u[n] + u[n-d] + fb*y[n-d] =====
__global__ __launch_bounds__(256) void allpass_kernel(const float* __restrict__ xin,
                                                      float* __restrict__ yout,
                                                      int d, int J, float inscale) {
  int tid = blockIdx.x * 256 + threadIdx.x;
  int total = 4 * d * J;
  if (tid >= total) return;
  int rch = tid / (d * J);
  int rem = tid - rch * (d * J);
  int j = rem / d;
  int p = rem - j * d;
  const float* xi = xin + (size_t)rch * NS;
  float* yo = yout + (size_t)rch * NS;
  int K = (NS - p + d - 1) / d;
  int kstart = j * CB;
  if (kstart >= K) return;
  int kend = kstart + CB; if (kend > K) kend = K;
  float yv = 0.f;
  int k;
  if (j == 0) { yo[p] = 0.f; k = 1; }              // k=0 output is exactly 0
  else        { k = kstart - RVW; }                // >= CB-RVW >= 1
  int n = k * d + p;
  if (j != 0) {
    #pragma unroll 8
    for (; k < kstart; ++k, n += d) {
      float u  = inscale * xi[n];
      float up = inscale * xi[n - d];
      yv = fmaf(FBC, yv, fmaf(-FBC, u, up));
    }
  }
  #pragma unroll 8
  for (; k < kend; ++k, n += d) {
    float u  = inscale * xi[n];
    float up = inscale * xi[n - d];
    yv = fmaf(FBC, yv, fmaf(-FBC, u, up));
    yo[n] = yv;
  }
}

// ===== Pan/volume gains =====
__global__ void gains_kernel(const float* __restrict__ vol, const float* __restrict__ pan,
                             float* __restrict__ g) {
  int t = threadIdx.x;
  if (t < 4) {
    float angle = (pan[t] + 1.0f) * 0.25f * 3.14159265358979323846f;
    g[2 * t]     = vol[t] * cosf(angle);
    g[2 * t + 1] = vol[t] * sinf(angle);
  }
}

// ===== Final mix: dry/wet blend for tracks 2,3; einsum over tracks; clip =====
__global__ __launch_bounds__(256) void mix_kernel(const float* __restrict__ cp,
                                                  const float* __restrict__ wet,
                                                  const float* __restrict__ g,
                                                  float* __restrict__ out) {
  int i = blockIdx.x * 256 + threadIdx.x;
  if (i >= NS / 4) return;
  size_t n = (size_t)i * 4;
  float g0 = g[0], g1 = g[1], g2 = g[2], g3 = g[3];
  float g4 = g[4], g5 = g[5], g6 = g[6], g7 = g[7];
  const float CEIL = 0.89125093813374556f;  // 10^(-1/20)
  float4 t0l = *(const float4*)(cp + 0 * (size_t)NS + n);
  float4 t0r = *(const float4*)(cp + 1 * (size_t)NS + n);
  float4 t1l = *(const float4*)(cp + 2 * (size_t)NS + n);
  float4 t1r = *(const float4*)(cp + 3 * (size_t)NS + n);
  float4 t2l = *(const float4*)(cp + 4 * (size_t)NS + n);
  float4 t2r = *(const float4*)(cp + 5 * (size_t)NS + n);
  float4 t3l = *(const float4*)(cp + 6 * (size_t)NS + n);
  float4 t3r = *(const float4*)(cp + 7 * (size_t)NS + n);
  float4 w2l = *(const float4*)(wet + 0 * (size_t)NS + n);
  float4 w2r = *(const float4*)(wet + 1 * (size_t)NS + n);
  float4 w3l = *(const float4*)(wet + 2 * (size_t)NS + n);
  float4 w3r = *(const float4*)(wet + 3 * (size_t)NS + n);
  float4 outl, outr;
  float* pl = &outl.x; float* pr = &outr.x;
  const float* a0 = &t0l.x; const float* a1 = &t0r.x;
  const float* a2 = &t1l.x; const float* a3 = &t1r.x;
  const float* a4 = &t2l.x; const float* a5 = &t2r.x;
  const float* a6 = &t3l.x; const float* a7 = &t3r.x;
  const float* b4 = &w2l.x; const float* b5 = &w2r.x;
  const float* b6 = &w3l.x; const float* b7 = &w3r.x;
  #pragma unroll
  for (int c = 0; c < 4; ++c) {
    float x4 = 0.7f * a4[c] + 0.3f * b4[c];
    float x5 = 0.7f * a5[c] + 0.3f * b5[c];
    float x6 = 0.7f * a6[c] + 0.3f * b6[c];
    float x7 = 0.7f * a7[c] + 0.3f * b7[c];
    float Lv = g0 * a0[c] + g2 * a2[c] + g4 * x4 + g6 * x6;
    float Rv = g1 * a1[c] + g3 * a3[c] + g5 * x5 + g7 * x7;
    pl[c] = fminf(fmaxf(Lv, -CEIL), CEIL);
    pr[c] = fminf(fmaxf(Rv, -CEIL), CEIL);
  }
  *(float4*)(out + n) = outl;
  *(float4*)(out + (size_t)NS + n) = outr;
}

// ---------------- Host side ----------------
static void peak_coefs(double f, double gdb, double q, float* o) {
  double A  = pow(10.0, gdb / 40.0);
  double w0 = 2.0 * M_PI * f / 48000.0;
  double al = sin(w0) / (2.0 * q);
  double a0 = 1.0 + al / A;
  o[0] = (float)((1.0 + al * A) / a0);
  o[1] = (float)(-2.0 * cos(w0) / a0);
  o[2] = (float)((1.0 - al * A) / a0);
  o[3] = (float)(-2.0 * cos(w0) / a0);
  o[4] = (float)((1.0 - al / A) / a0);
}

extern "C" void kernel_launch(void* const* d_in, const int* in_sizes, int n_in,
                              void* d_out, int out_size, void* d_ws, size_t ws_size,
                              hipStream_t stream) {
  const float* tracks = (const float*)d_in[0];
  const float* vols   = (const float*)d_in[1];
  const float* pans   = (const float*)d_in[2];
  float* out = (float*)d_out;
  float* w = (float*)d_ws;
  // ws layout (floats):
  //  [0,8N)   : XT (transposed input) -> overwritten by comp output Y (natural)
  //  [8N,16N) : ET (EQ output, chunk-major) -> after comp: comb acc [8N,12N),
  //             ap240 out [12N,16N), ap81 out back to [8N,12N) = wet
  //  gains at [12N, 12N+8) after ap81 (ap240 buffer dead)
  float* XT   = w;
  float* ET   = w + (size_t)8 * NS;
  float* cpbuf = w;                       // comp output, natural layout
  float* combb = w + (size_t)8 * NS;      // comb accumulator (ET dead)
  float* apb   = w + (size_t)12 * NS;     // allpass d=240 output
  float* wet2  = w + (size_t)8 * NS;      // allpass d=81 output (comb acc dead)
  float* gbuf  = w + (size_t)12 * NS;     // gains (apb dead after ap81)

  Coefs cf;
  const float ident[5] = {1.f, 0.f, 0.f, 0.f, 0.f};
  const double P[4][3][3] = {
    {{300, -3, 0.7}, {3000, 3, 1.0}, {8000, 2, 0.7}},   // voice
    {{80, 2, 0.7},   {5000, 1, 1.0}, {0, 0, 0}},        // music
    {{200, -2, 0.7}, {6000, -1, 0.7}, {0, 0, 0}},       // ambient
    {{1000, 2, 1.0}, {0, 0, 0},      {0, 0, 0}},        // fx
  };
  const int nb[4] = {3, 2, 2, 1};
  for (int t = 0; t < 4; ++t)
    for (int s = 0; s < 3; ++s) {
      if (s < nb[t]) peak_coefs(P[t][s][0], P[t][s][1], P[t][s][2], cf.c[s][t]);
      else for (int q = 0; q < 5; ++q) cf.c[s][t][q] = ident[q];
    }

  CompC cc;
  double atk = exp(-1.0 / 480.0), rel = exp(-1.0 / 4800.0);
  cc.atk  = (float)atk;  cc.rel  = (float)rel;
  cc.oatk = (float)(1.0 - atk); cc.orel = (float)(1.0 - rel);
  cc.invt = (float)(1.0 / (pow(10.0, -18.0 / 20.0) + 1e-8));

  hipLaunchKernelGGL(transpose_in, dim3(8 * TI * TJ), dim3(256), 0, stream,
                     tracks, XT);
  hipLaunchKernelGGL(eq_kernel, dim3(8 * NC / 64), dim3(64), 0, stream,
                     XT, ET, cf);
  hipLaunchKernelGGL(comp_kernel, dim3(8 * NC / 64), dim3(64), 0, stream,
                     ET, cpbuf, cc);

  const int combd[4] = {1440, 1627, 1828, 2030};  // int(1440*{1,1.13,1.27,1.41})
  for (int i = 0; i < 4; ++i) {
    int d = combd[i];
    int K = (NS + d - 1) / d;
    int J = (K + CB - 1) / CB;
    int total = 4 * d * J;
    hipLaunchKernelGGL(comb_kernel, dim3((total + 255) / 256), dim3(256), 0, stream,
                       cpbuf, combb, d, J, (i == 0) ? 1 : 0);
  }
  {
    int d = 240, K = (NS + d - 1) / d, J = (K + CB - 1) / CB, total = 4 * d * J;
    hipLaunchKernelGGL(allpass_kernel, dim3((total + 255) / 256), dim3(256), 0, stream,
                       combb, apb, d, J, 0.25f);  // fold the /4 comb average into input
  }
  {
    int d = 81, K = (NS + d - 1) / d, J = (K + CB - 1) / CB, total = 4 * d * J;
    hipLaunchKernelGGL(allpass_kernel, dim3((total + 255) / 256), dim3(256), 0, stream,
                       apb, wet2, d, J, 1.0f);
  }
  hipLaunchKernelGGL(gains_kernel, dim3(1), dim3(64), 0, stream, vols, pans, gbuf);
  hipLaunchKernelGGL(mix_kernel, dim3((NS / 4 + 255) / 256), dim3(256), 0, stream,
                     cpbuf, wet2, gbuf, out);
}